// Round 1
// 643.240 us; speedup vs baseline: 1.0919x; 1.0919x over previous
//
#include <hip/hip_runtime.h>
#include <hip/hip_bf16.h>
#include <cstdint>

#define B_SZ 1000
#define D_SZ 512
#define N_SZ 100000
#define F_SZ 50
#define NEGV -1000000.0f

#define BN 128
#define NT_N 782   // ceil(100000/128)
#define NT_B 8
#define CAP 64
#define G_MAIN (NT_B * NT_N)   // 6256
#define G_FULL 6208            // 97*64 : full 8x8 swizzle groups (tile_n 0..775)

#define T_OFF 0
#define CNT_OFF 4096
#define ENT_OFF 32768
#define QB_OFF  0x200000            // qb: 1024*512*2 = 1 MB
#define RT_OFF  0x400000            // rhsT: 100096*512*2 = 102.5 MB
#define RT_ROWS 100096              // 782*128 = 100096 (pad rows zeroed)

typedef __bf16 bf16x8 __attribute__((ext_vector_type(8)));
typedef __bf16 bf16x4 __attribute__((ext_vector_type(4)));
typedef float f32x4 __attribute__((ext_vector_type(4)));

__device__ __forceinline__ void gl_lds16(const void* g, void* l){
  __builtin_amdgcn_global_load_lds(
      (const __attribute__((address_space(1))) unsigned int*)g,
      (__attribute__((address_space(3))) unsigned int*)l, 16, 0, 0);
}
__device__ __forceinline__ float f4c(const float4& v, int c){
  switch(c){ case 0: return v.x; case 1: return v.y; case 2: return v.z; default: return v.w; }
}

// ---------------- zero t/cnt regions (ws poisoned 0xAA each call) ----------
__global__ void zero_ws(int* p){ p[blockIdx.x * 256 + threadIdx.x] = 0; }

// ---------------- q f32 [1000][512] -> qb bf16 [1024][512], pad rows 0 -----
__global__ void cvtq_kernel(const float* __restrict__ q, __bf16* __restrict__ qb){
  int g = blockIdx.x * 256 + threadIdx.x;
  int row = g >> 6;
  int k0 = (g & 63) * 8;
  float4 v0 = make_float4(0.f,0.f,0.f,0.f), v1 = v0;
  if(row < B_SZ){
    v0 = *(const float4*)(q + (size_t)row * D_SZ + k0);
    v1 = *(const float4*)(q + (size_t)row * D_SZ + k0 + 4);
  }
  bf16x8 w = { (__bf16)v0.x,(__bf16)v0.y,(__bf16)v0.z,(__bf16)v0.w,
               (__bf16)v1.x,(__bf16)v1.y,(__bf16)v1.z,(__bf16)v1.w };
  *(bf16x8*)(qb + (size_t)row * D_SZ + k0) = w;
}

// ---------------- rhs f32 [512][100000] -> rhsT bf16 [100096][512] ---------
__global__ __launch_bounds__(256)
void tconv_kernel(const float* __restrict__ rhs, __bf16* __restrict__ rhsT){
  __shared__ float tile[64][65];
  const int tn = blockIdx.x;           // 0..1563  (1564*64 = 100096)
  const int tk = blockIdx.y;           // 0..7
  const int tid = threadIdx.x;
  const int n0 = tn * 64, k0 = tk * 64;
  // read phase: coalesced along n
  {
    const int nc = (tid & 15) * 4;
    const int kr0 = tid >> 4;          // 0..15
    #pragma unroll
    for(int i = 0; i < 4; i++){
      int kr = kr0 + i * 16;
      int n = n0 + nc;
      float4 v = (n < N_SZ) ? *(const float4*)(rhs + (size_t)(k0 + kr) * N_SZ + n)
                            : make_float4(0.f,0.f,0.f,0.f);
      tile[kr][nc+0] = v.x; tile[kr][nc+1] = v.y;
      tile[kr][nc+2] = v.z; tile[kr][nc+3] = v.w;
    }
  }
  __syncthreads();
  // write phase: coalesced along k
  {
    const int nl = tid >> 2;           // 0..63
    const int kc = (tid & 3) * 16;
    float a[16];
    #pragma unroll
    for(int j = 0; j < 16; j++) a[j] = tile[kc + j][nl];
    bf16x8 w0, w1;
    #pragma unroll
    for(int j = 0; j < 8; j++){ w0[j] = (__bf16)a[j]; w1[j] = (__bf16)a[8 + j]; }
    __bf16* dst = rhsT + (size_t)(n0 + nl) * D_SZ + k0 + kc;
    *(bf16x8*)dst = w0;
    *(bf16x8*)(dst + 8) = w1;
  }
}

// ---------------- t[b] = q[b] . rhs[:, target[b]] (f32 exact) --------------
__global__ void t_kernel(const float* __restrict__ q, const float* __restrict__ rhs,
                         const int* __restrict__ target, float* __restrict__ t){
  int b = blockIdx.x;
  int tid = threadIdx.x;
  int tj = target[b];
  const float* qb = q + (size_t)b * D_SZ;
  float p = qb[tid] * rhs[(size_t)tid * N_SZ + tj]
          + qb[tid + 256] * rhs[(size_t)(tid + 256) * N_SZ + tj];
  for(int off = 32; off; off >>= 1) p += __shfl_down(p, off);
  __shared__ float red[4];
  if((tid & 63) == 0) red[tid >> 6] = p;
  __syncthreads();
  if(tid == 0) t[b] = red[0] + red[1] + red[2] + red[3];
}

// ---------------- dedupe filter∪target, bin into owning block --------------
__global__ void prep_kernel(const int* __restrict__ filt, const int* __restrict__ target,
                            const float* __restrict__ t, int* __restrict__ cnt,
                            unsigned* __restrict__ entries, float* __restrict__ out){
  int b = blockIdx.x * blockDim.x + threadIdx.x;
  if(b >= B_SZ) return;
  int idx[F_SZ + 1];
  for(int i = 0; i < F_SZ; i++) idx[i] = filt[b * F_SZ + i];
  idx[F_SZ] = target[b];
  float tb = t[b];
  int nuniq = 0;
  for(int i = 0; i <= F_SZ; i++){
    int j = idx[i];
    bool first = true;
    for(int k = 0; k < i; k++) if(idx[k] == j){ first = false; break; }
    if(!first) continue;
    nuniq++;
    int bid = (b >> 7) * NT_N + (j >> 7);
    int pos = atomicAdd(&cnt[bid], 1);
    if(pos < CAP)
      entries[(size_t)bid * CAP + pos] = (unsigned)(((b & 127) << 7) | (j & 127));
  }
  out[b] = 1.0f + ((NEGV >= tb) ? (float)nuniq : 0.0f);
}

// ---------------- fused MFMA GEMM + rank count -----------------------------
// MODE 1: B from pre-transposed bf16 rhsT via global_load_lds.
//   NEW: depth-1 double-buffered pipeline, raw s_barrier + counted vmcnt(4)
//   (never drain to 0 in steady state), and an XCD-locality block swizzle so
//   the 8 tile_b sharers of each rhsT N-strip land on ONE XCD's L2.
// MODE 0: B staged from f32 rhs with in-register cvt (fallback, old 2-sync loop)
// LDS tile layout: 16B slot s = kq*128 + row  (kq = k-octet 0..3, row = m or n)
template<int MODE>
__global__ __launch_bounds__(256)
void main_kernel(const float* __restrict__ rhs, const __bf16* __restrict__ rhsT,
                 const __bf16* __restrict__ qb, const float* __restrict__ t,
                 const int* __restrict__ cnt, const unsigned* __restrict__ entries,
                 float* __restrict__ out){
  __shared__ __bf16 Ab[2][4096];   // 16 KB (MODE 0 uses [0] only)
  __shared__ __bf16 Bb[2][4096];   // 16 KB
  __shared__ float tl[128];
  __shared__ unsigned lent[CAP];
  __shared__ int lcnt_s;

  // ---- XCD-locality swizzle (bijective):
  // hardware block h -> XCD h%8 (round-robin). Group 64 consecutive h into
  // 8 tile_n x 8 tile_b; tile_n = 8*(h>>6) + (h&7)  => all 8 sharers of a
  // strip have identical h%8 (same XCD) and adjacent slots (consecutive h>>3).
  const int h = blockIdx.x;
  int tile_b, tile_n;
  if(h < G_FULL){ tile_n = ((h >> 6) << 3) | (h & 7); tile_b = (h >> 3) & 7; }
  else { int h2 = h - G_FULL; tile_n = 776 + (h2 >> 3); tile_b = h2 & 7; }

  const int bid = tile_b * NT_N + tile_n;
  const int tid = threadIdx.x;
  const int n0 = tile_n * BN;
  const int b0 = tile_b * BN;

  if(tid < 128){ int b = b0 + tid; tl[tid] = (b < B_SZ) ? t[b] : 0.f; }
  if(tid == 0){ int c = cnt[bid]; lcnt_s = (c > CAP) ? CAP : c; }
  if(tid < CAP) lent[tid] = entries[(size_t)bid * CAP + tid];

  const int lane = tid & 63, wave = tid >> 6;
  const int quad = lane >> 4, l15 = lane & 15;
  const int wr0 = (wave >> 1) * 64;
  const int wc0 = (wave & 1) * 64;
  const int wA = wave * 1024;        // wave-uniform LDS slot base (bf16 elems)

  // ---- async staging setup: wave w stages k-octet w for rows 0..127
  const __bf16* gA0 = qb + ((size_t)(b0 + lane) * D_SZ) + wave * 8;
  const __bf16* gA1 = gA0 + (size_t)64 * D_SZ;
  const __bf16* gB0 = rhsT + ((size_t)(n0 + lane) * D_SZ) + wave * 8;
  const __bf16* gB1 = gB0 + (size_t)64 * D_SZ;

  // ---- fallback B staging: thread covers k-quad kb (k=4kb..4kb+3) x 4 n ----
  const int g2 = tid & 31;           // n-quad
  const int kb = tid >> 5;           // 0..7
  const int nbc = n0 + g2 * 4;
  const bool bok = nbc < N_SZ;       // N%4==0: group all-in or all-out
  const float4 fz = make_float4(0.f, 0.f, 0.f, 0.f);
  float4 pv[4];
  if(MODE == 0){
    #pragma unroll
    for(int i = 0; i < 4; i++)
      pv[i] = bok ? *(const float4*)(rhs + (size_t)(4 * kb + i) * N_SZ + nbc) : fz;
  }

  f32x4 acc[4][4];
  #pragma unroll
  for(int i = 0; i < 4; i++)
    #pragma unroll
    for(int j = 0; j < 4; j++)
      acc[i][j] = (f32x4){0.f, 0.f, 0.f, 0.f};

  if(MODE == 1){
    // make tl/lent/lcnt_s writes + their source loads drain once, then never
    // use __syncthreads (and its vmcnt(0)) again inside the pipeline.
    __syncthreads();
    // ---- prologue: stage tile 0 into buffer 0 (4 loads/wave in flight)
    gl_lds16(gA0, &Ab[0][wA]); gl_lds16(gA1, &Ab[0][wA + 512]);
    gl_lds16(gB0, &Bb[0][wA]); gl_lds16(gB1, &Bb[0][wA + 512]);
    gA0 += 32; gA1 += 32; gB0 += 32; gB1 += 32;

    #pragma unroll 2
    for(int kt = 0; kt < 16; kt++){
      const int cur = kt & 1, nxt = cur ^ 1;
      if(kt < 15){
        // issue NEXT tile's loads (8 in flight), then wait only current 4
        gl_lds16(gA0, &Ab[nxt][wA]); gl_lds16(gA1, &Ab[nxt][wA + 512]);
        gl_lds16(gB0, &Bb[nxt][wA]); gl_lds16(gB1, &Bb[nxt][wA + 512]);
        gA0 += 32; gA1 += 32; gB0 += 32; gB1 += 32;
        asm volatile("s_waitcnt vmcnt(4)" ::: "memory");
      } else {
        asm volatile("s_waitcnt vmcnt(0)" ::: "memory");
      }
      __builtin_amdgcn_s_barrier();        // current tile resident for ALL waves
      asm volatile("" ::: "memory");       // pin frag reads below the barrier

      bf16x8 af[4], bfr[4];
      #pragma unroll
      for(int i = 0; i < 4; i++)
        af[i] = *(bf16x8*)&Ab[cur][quad * 1024 + (size_t)(wr0 + i * 16 + l15) * 8];
      #pragma unroll
      for(int j = 0; j < 4; j++)
        bfr[j] = *(bf16x8*)&Bb[cur][quad * 1024 + (size_t)(wc0 + j * 16 + l15) * 8];
      #pragma unroll
      for(int i = 0; i < 4; i++)
        #pragma unroll
        for(int j = 0; j < 4; j++)
          acc[i][j] = __builtin_amdgcn_mfma_f32_16x16x32_bf16(af[i], bfr[j], acc[i][j], 0, 0, 0);

      // all my ds_reads of buf[cur] complete before I arrive at the barrier,
      // so after it the next iteration may overwrite buf[cur].
      asm volatile("s_waitcnt lgkmcnt(0)" ::: "memory");
      __builtin_amdgcn_s_barrier();
      asm volatile("" ::: "memory");
    }
  } else {
    // ---------------- MODE 0 fallback: original 2-syncthreads loop ----------
    for(int kt = 0; kt < 16; kt++){
      __syncthreads();                  // prev frag reads complete
      gl_lds16(gA0, &Ab[0][wA]); gl_lds16(gA1, &Ab[0][wA + 512]);
      gA0 += 32; gA1 += 32;
      // stage prefetched f32 regs -> cvt -> LDS (static indexing only)
      #pragma unroll
      for(int c = 0; c < 4; c++){
        bf16x4 w = { (__bf16)f4c(pv[0], c), (__bf16)f4c(pv[1], c),
                     (__bf16)f4c(pv[2], c), (__bf16)f4c(pv[3], c) };
        *(bf16x4*)(&Bb[0][0] + (kb >> 1) * 1024 + (size_t)(g2 * 4 + c) * 8 + (kb & 1) * 4) = w;
      }
      __syncthreads();                  // drains vmcnt(0): tiles resident
      if(kt < 15){
        const float* p_ = rhs + (size_t)((kt + 1) * 32 + 4 * kb) * N_SZ + nbc;
        #pragma unroll
        for(int i = 0; i < 4; i++)
          pv[i] = bok ? *(const float4*)(p_ + (size_t)i * N_SZ) : fz;
      }
      bf16x8 af[4], bfr[4];
      #pragma unroll
      for(int i = 0; i < 4; i++)
        af[i] = *(bf16x8*)&Ab[0][quad * 1024 + (size_t)(wr0 + i * 16 + l15) * 8];
      #pragma unroll
      for(int j = 0; j < 4; j++)
        bfr[j] = *(bf16x8*)&Bb[0][quad * 1024 + (size_t)(wc0 + j * 16 + l15) * 8];
      #pragma unroll
      for(int i = 0; i < 4; i++)
        #pragma unroll
        for(int j = 0; j < 4; j++)
          acc[i][j] = __builtin_amdgcn_mfma_f32_16x16x32_bf16(af[i], bfr[j], acc[i][j], 0, 0, 0);
    }
  }

  // ---- epilogue: count s >= t_b (C/D layout: col=lane&15, row=quad*4+reg) --
  int cntv[4][4];
  #pragma unroll
  for(int rt = 0; rt < 4; rt++){
    #pragma unroll
    for(int r = 0; r < 4; r++){
      int row = wr0 + rt * 16 + quad * 4 + r;
      float trow = tl[row];
      int c = 0;
      #pragma unroll
      for(int ct = 0; ct < 4; ct++){
        int ncol = n0 + wc0 + ct * 16 + l15;
        if(ncol < N_SZ && acc[rt][ct][r] >= trow) c++;
      }
      cntv[rt][r] = c;
    }
  }
  int lc = lcnt_s;
  for(int e = 0; e < lc; e++){
    unsigned en = lent[e];
    int row = en >> 7;
    int col = en & 127;
    int rr = row - wr0;
    int ccl = col - wc0;
    if(rr >= 0 && rr < 64 && ccl >= 0 && ccl < 64 &&
       quad == ((rr & 15) >> 2) && l15 == (ccl & 15)){
      int rt = rr >> 4, ct = ccl >> 4, r = rr & 3;
      float trow = tl[row];
      #pragma unroll
      for(int i = 0; i < 4; i++)
        #pragma unroll
        for(int j = 0; j < 4; j++)
          #pragma unroll
          for(int k = 0; k < 4; k++)
            if(i == rt && j == ct && k == r && acc[i][j][k] >= trow)
              cntv[i][k]--;
    }
  }
  #pragma unroll
  for(int rt = 0; rt < 4; rt++){
    #pragma unroll
    for(int r = 0; r < 4; r++){
      int c = cntv[rt][r];
      c += __shfl_xor(c, 1);
      c += __shfl_xor(c, 2);
      c += __shfl_xor(c, 4);
      c += __shfl_xor(c, 8);
      if(l15 == 0){
        int bg = b0 + wr0 + rt * 16 + quad * 4 + r;
        if(bg < B_SZ) atomicAdd(&out[bg], (float)c);
      }
    }
  }
}

extern "C" void kernel_launch(void* const* d_in, const int* in_sizes, int n_in,
                              void* d_out, int out_size, void* d_ws, size_t ws_size,
                              hipStream_t stream){
  const float* q    = (const float*)d_in[0];
  const float* rhs  = (const float*)d_in[1];
  const int* filt   = (const int*)d_in[2];
  const int* target = (const int*)d_in[3];
  float* out = (float*)d_out;
  char* ws = (char*)d_ws;
  float* t          = (float*)(ws + T_OFF);
  int* cnt          = (int*)(ws + CNT_OFF);
  unsigned* entries = (unsigned*)(ws + ENT_OFF);
  __bf16* qb        = (__bf16*)(ws + QB_OFF);
  __bf16* rhsT      = (__bf16*)(ws + RT_OFF);

  const size_t need = (size_t)RT_OFF + (size_t)RT_ROWS * D_SZ * 2;   // ~106.7 MB
  const bool big = ws_size >= need;

  zero_ws<<<32, 256, 0, stream>>>((int*)ws);
  cvtq_kernel<<<256, 256, 0, stream>>>(q, qb);
  t_kernel<<<B_SZ, 256, 0, stream>>>(q, rhs, target, t);
  prep_kernel<<<(B_SZ + 255) / 256, 256, 0, stream>>>(filt, target, t, cnt, entries, out);
  if(big){
    tconv_kernel<<<dim3(RT_ROWS / 64, 8), 256, 0, stream>>>(rhs, rhsT);
    main_kernel<1><<<G_MAIN, 256, 0, stream>>>(rhs, rhsT, qb, t, cnt, entries, out);
  } else {
    main_kernel<0><<<G_MAIN, 256, 0, stream>>>(rhs, rhsT, qb, t, cnt, entries, out);
  }
}

// Round 2
// 622.015 us; speedup vs baseline: 1.1292x; 1.0341x over previous
//
#include <hip/hip_runtime.h>
#include <hip/hip_bf16.h>
#include <cstdint>

#define B_SZ 1000
#define D_SZ 512
#define N_SZ 100000
#define F_SZ 50
#define NEGV -1000000.0f

// ---- 256x256 main tile geometry ----
#define BM2 256
#define NT_N2 391            // 391*256 = 100096
#define NT_B2 4              // 1024/256
#define G2 (NT_B2 * NT_N2)   // 1564 blocks
#define CAP2 160             // avg entries/bin ~32.6; 160 = 22 sigma headroom

#define T_OFF 0
#define CNT_OFF 4096
#define ENT_OFF 32768            // entries: 1564*160*4B = 1.0 MB (< 2MB gap)
#define QB_OFF  0x200000         // qb2: 4*8*8*256*16B = 2 MB (ends exactly at RT_OFF)
#define RT_OFF  0x400000         // rhsT2: 391 * 256KB = 102.5 MB
#define RT_ROWS 100096

typedef __bf16 bf16x8 __attribute__((ext_vector_type(8)));
typedef float f32x4 __attribute__((ext_vector_type(4)));

__device__ __forceinline__ void gl_lds16(const void* g, void* l){
  __builtin_amdgcn_global_load_lds(
      (const __attribute__((address_space(1))) unsigned int*)g,
      (__attribute__((address_space(3))) unsigned int*)l, 16, 0, 0);
}

// ---------------- zero t/cnt regions (ws poisoned 0xAA each call) ----------
__global__ void zero_ws(int* p){ p[blockIdx.x * 256 + threadIdx.x] = 0; }

// ---------------- q f32 [1000][512] -> qb2 tiled bf16 ----------------------
// qb2 layout: [mt 4][kt 8][kq 8][row 256][8 bf16]  (LDS-tile order, pads 0)
__global__ void cvtq_kernel(const float* __restrict__ q, __bf16* __restrict__ qb){
  int g = blockIdx.x * 256 + threadIdx.x;
  int row = g >> 6;                 // 0..1023
  int k0 = (g & 63) * 8;
  float4 v0 = make_float4(0.f,0.f,0.f,0.f), v1 = v0;
  if(row < B_SZ){
    v0 = *(const float4*)(q + (size_t)row * D_SZ + k0);
    v1 = *(const float4*)(q + (size_t)row * D_SZ + k0 + 4);
  }
  bf16x8 w = { (__bf16)v0.x,(__bf16)v0.y,(__bf16)v0.z,(__bf16)v0.w,
               (__bf16)v1.x,(__bf16)v1.y,(__bf16)v1.z,(__bf16)v1.w };
  int mt = row >> 8, r = row & 255;
  int kt = k0 >> 6, kq = (k0 >> 3) & 7;
  *(bf16x8*)(qb + ((size_t)(mt*8 + kt)*8 + kq) * 2048 + (size_t)r * 8) = w;
}

// ---------------- rhs f32 [512][100000] -> rhsT2 tiled bf16 ----------------
// rhsT2 layout: [nt 391][kt 8][kq 8][row 256][8 bf16]
__global__ __launch_bounds__(256)
void tconv_kernel(const float* __restrict__ rhs, __bf16* __restrict__ rhsT){
  __shared__ float tile[64][65];
  const int tn = blockIdx.x;           // 0..1563
  const int tk = blockIdx.y;           // 0..7 (one k-tile per block)
  const int tid = threadIdx.x;
  const int n0 = tn * 64, k0 = tk * 64;
  // read phase: coalesced along n
  {
    const int nc = (tid & 15) * 4;
    const int kr0 = tid >> 4;          // 0..15
    #pragma unroll
    for(int i = 0; i < 4; i++){
      int kr = kr0 + i * 16;
      int n = n0 + nc;
      float4 v = (n < N_SZ) ? *(const float4*)(rhs + (size_t)(k0 + kr) * N_SZ + n)
                            : make_float4(0.f,0.f,0.f,0.f);
      tile[kr][nc+0] = v.x; tile[kr][nc+1] = v.y;
      tile[kr][nc+2] = v.z; tile[kr][nc+3] = v.w;
    }
  }
  __syncthreads();
  // write phase: lane = n (perfectly coalesced 1KB per kq region)
  {
    const int nl = tid & 63;
    const int kc = (tid >> 6) * 16;    // 0,16,32,48
    float a[16];
    #pragma unroll
    for(int j = 0; j < 16; j++) a[j] = tile[kc + j][nl];
    bf16x8 w0, w1;
    #pragma unroll
    for(int j = 0; j < 8; j++){ w0[j] = (__bf16)a[j]; w1[j] = (__bf16)a[8 + j]; }
    const int ng = n0 + nl;
    const int nt = ng >> 8, r = ng & 255;
    const int kq0 = kc >> 3;           // 0,2,4,6
    __bf16* dst = rhsT + ((size_t)(nt*8 + tk)*8 + kq0) * 2048 + (size_t)r * 8;
    *(bf16x8*)dst = w0;
    *(bf16x8*)(dst + 2048) = w1;       // kq0+1
  }
}

// ---------------- t[b] = q[b] . rhs[:, target[b]] (f32 exact) --------------
__global__ void t_kernel(const float* __restrict__ q, const float* __restrict__ rhs,
                         const int* __restrict__ target, float* __restrict__ t){
  int b = blockIdx.x;
  int tid = threadIdx.x;
  int tj = target[b];
  const float* qb = q + (size_t)b * D_SZ;
  float p = qb[tid] * rhs[(size_t)tid * N_SZ + tj]
          + qb[tid + 256] * rhs[(size_t)(tid + 256) * N_SZ + tj];
  for(int off = 32; off; off >>= 1) p += __shfl_down(p, off);
  __shared__ float red[4];
  if((tid & 63) == 0) red[tid >> 6] = p;
  __syncthreads();
  if(tid == 0) t[b] = red[0] + red[1] + red[2] + red[3];
}

// ---------------- dedupe filter∪target, bin into owning 256x256 tile -------
__global__ void prep_kernel(const int* __restrict__ filt, const int* __restrict__ target,
                            const float* __restrict__ t, int* __restrict__ cnt,
                            unsigned* __restrict__ entries, float* __restrict__ out){
  int b = blockIdx.x * blockDim.x + threadIdx.x;
  if(b >= B_SZ) return;
  int idx[F_SZ + 1];
  for(int i = 0; i < F_SZ; i++) idx[i] = filt[b * F_SZ + i];
  idx[F_SZ] = target[b];
  float tb = t[b];
  int nuniq = 0;
  for(int i = 0; i <= F_SZ; i++){
    int j = idx[i];
    bool first = true;
    for(int k = 0; k < i; k++) if(idx[k] == j){ first = false; break; }
    if(!first) continue;
    nuniq++;
    int bid = (b >> 8) * NT_N2 + (j >> 8);
    int pos = atomicAdd(&cnt[bid], 1);
    if(pos < CAP2)
      entries[(size_t)bid * CAP2 + pos] = (unsigned)(((b & 255) << 8) | (j & 255));
  }
  out[b] = 1.0f + ((NEGV >= tb) ? (float)nuniq : 0.0f);
}

// ---------------- fused 256x256 MFMA GEMM + rank count (8-phase-style) -----
// 8 waves (2M x 4N), per-wave 128x64 output (acc[8][4] f32x4).
// BK=64: double-buffered 2x(32KB A + 32KB B); per K-tile: issue next tile's
// 8 global_load_lds, s_waitcnt vmcnt(8) (counted - loads stay in flight a
// full K-tile of compute), raw s_barrier. Filter corrections via LDS bitmap.
__global__ __launch_bounds__(512, 2)
void main_kernel(const __bf16* __restrict__ rhsT, const __bf16* __restrict__ qb,
                 const float* __restrict__ t, const int* __restrict__ cnt,
                 const unsigned* __restrict__ entries, float* __restrict__ out){
  __shared__ __attribute__((aligned(16))) __bf16 A2[2][16384];  // 64 KB
  __shared__ __attribute__((aligned(16))) __bf16 B2[2][16384];  // 64 KB
  __shared__ float tl[256];
  __shared__ unsigned lent[CAP2];
  __shared__ unsigned bm[2048];      // 256 rows x 256 cols bit map (8 KB)
  __shared__ int rowc[256];
  __shared__ int lcnt_s;

  // ---- bijective XCD swizzle (nwg=1564 = 8*195+4; m204 variant):
  // xcd h%8 gets a contiguous wg chunk; 4 consecutive wg share one B-strip.
  const int h = blockIdx.x;
  const int xcd = h & 7, slot = h >> 3;
  const int wg = (xcd < 4 ? xcd * 196 : 784 + (xcd - 4) * 195) + slot;
  const int tile_n = wg >> 2;        // 0..390
  const int tile_b = wg & 3;         // 0..3
  const int bid = tile_b * NT_N2 + tile_n;
  const int tid = threadIdx.x;
  const int n0 = tile_n * BM2;
  const int b0 = tile_b * BM2;

  if(tid < 256){ int b = b0 + tid; tl[tid] = (b < B_SZ) ? t[b] : 0.f; rowc[tid] = 0; }
  if(tid < CAP2) lent[tid] = entries[(size_t)bid * CAP2 + tid];
  if(tid == 0){ int c = cnt[bid]; lcnt_s = (c > CAP2) ? CAP2 : c; }
  bm[tid] = 0; bm[tid + 512] = 0; bm[tid + 1024] = 0; bm[tid + 1536] = 0;

  const int wave = tid >> 6, lane = tid & 63;
  const int quad = lane >> 4, l15 = lane & 15;
  const int wm = wave >> 2, wn = wave & 3;   // 2 x 4 wave grid

  // staging source pointers (linear copy: global layout == LDS layout)
  const __bf16* pA = qb   + (size_t)tile_b * 131072 + (size_t)tid * 8;
  const __bf16* pB = rhsT + (size_t)tile_n * 131072 + (size_t)tid * 8;

  f32x4 acc[8][4];
  #pragma unroll
  for(int i = 0; i < 8; i++)
    #pragma unroll
    for(int j = 0; j < 4; j++)
      acc[i][j] = (f32x4){0.f, 0.f, 0.f, 0.f};

  __syncthreads();                 // drain table loads (vmcnt(0)) pre-pipeline
  {                                // mark filter bitmap (LDS atomics, overlaps staging)
    int lc = lcnt_s;
    if(tid < lc){
      unsigned en = lent[tid];
      unsigned row = en >> 8, col = en & 255;
      atomicOr(&bm[row * 8 + (col >> 5)], 1u << (col & 31));
    }
  }
  // ---- prologue: stage K-tile 0 into buffer 0 (8 loads/thread in flight)
  #pragma unroll
  for(int j = 0; j < 4; j++){
    gl_lds16(pA + j * 4096, &A2[0][j * 4096 + tid * 8]);
    gl_lds16(pB + j * 4096, &B2[0][j * 4096 + tid * 8]);
  }

  #pragma unroll
  for(int kt = 0; kt < 8; kt++){
    const int cur = kt & 1, nxt = cur ^ 1;
    if(kt < 7){
      #pragma unroll
      for(int j = 0; j < 4; j++){
        gl_lds16(pA + (kt + 1) * 16384 + j * 4096, &A2[nxt][j * 4096 + tid * 8]);
        gl_lds16(pB + (kt + 1) * 16384 + j * 4096, &B2[nxt][j * 4096 + tid * 8]);
      }
      asm volatile("s_waitcnt vmcnt(8)" ::: "memory");   // tile kt resident (mine)
    } else {
      asm volatile("s_waitcnt vmcnt(0)" ::: "memory");
    }
    __builtin_amdgcn_s_barrier();                        // resident for all waves
    asm volatile("" ::: "memory");

    #pragma unroll
    for(int ks = 0; ks < 2; ks++){
      const int kq = ks * 4 + quad;
      bf16x8 a_[8], b_[4];
      #pragma unroll
      for(int i = 0; i < 8; i++)
        a_[i] = *(const bf16x8*)&A2[cur][(size_t)kq * 2048 + (size_t)(wm*128 + i*16 + l15) * 8];
      #pragma unroll
      for(int j = 0; j < 4; j++)
        b_[j] = *(const bf16x8*)&B2[cur][(size_t)kq * 2048 + (size_t)(wn*64 + j*16 + l15) * 8];
      __builtin_amdgcn_s_setprio(1);
      #pragma unroll
      for(int i = 0; i < 8; i++)
        #pragma unroll
        for(int j = 0; j < 4; j++)
          acc[i][j] = __builtin_amdgcn_mfma_f32_16x16x32_bf16(a_[i], b_[j], acc[i][j], 0, 0, 0);
      __builtin_amdgcn_s_setprio(0);
    }
    asm volatile("s_waitcnt lgkmcnt(0)" ::: "memory");   // my reads of buf[cur] done
    __builtin_amdgcn_s_barrier();                        // all waves done: nxt-writes safe
    asm volatile("" ::: "memory");
  }

  // ---- epilogue: count s >= t_row, excluding bitmap-marked filter entries --
  // C/D layout: col = l15 (+16j), row = quad*4 + r (+16i) [verified mapping]
  #pragma unroll
  for(int i = 0; i < 8; i++){
    #pragma unroll
    for(int r = 0; r < 4; r++){
      const int row = wm*128 + i*16 + quad*4 + r;
      const float trow = tl[row];
      const unsigned w01 = bm[row * 8 + wn * 2];
      const unsigned w23 = bm[row * 8 + wn * 2 + 1];
      int c = 0;
      bool ge[4];
      #pragma unroll
      for(int j = 0; j < 4; j++){
        int ncol = n0 + wn*64 + j*16 + l15;
        ge[j] = (ncol < N_SZ) && (acc[i][j][r] >= trow);
        c += ge[j] ? 1 : 0;
      }
      if(w01 | w23){                      // rare (~12% of (i,r) per wave)
        #pragma unroll
        for(int j = 0; j < 4; j++){
          unsigned w = (j < 2) ? w01 : w23;
          if(((w >> ((j & 1) * 16 + l15)) & 1u) && ge[j]) c--;
        }
      }
      c += __shfl_xor(c, 1);
      c += __shfl_xor(c, 2);
      c += __shfl_xor(c, 4);
      c += __shfl_xor(c, 8);
      if(l15 == 0) atomicAdd(&rowc[row], c);
    }
  }
  __syncthreads();
  if(tid < 256){
    int bg = b0 + tid, c = rowc[tid];
    if(bg < B_SZ && c) atomicAdd(&out[bg], (float)c);
  }
}

// ---------------- correctness fallback (small ws): plain f32 counting ------
__global__ __launch_bounds__(256)
void fallback_kernel(const float* __restrict__ q, const float* __restrict__ rhs,
                     const int* __restrict__ filt, const int* __restrict__ target,
                     const float* __restrict__ t, float* __restrict__ out){
  const int b = blockIdx.x;
  const int tid = threadIdx.x;
  __shared__ float qs[D_SZ];
  __shared__ int fs[F_SZ + 1];
  __shared__ float tbs;
  qs[tid] = q[(size_t)b * D_SZ + tid];
  qs[tid + 256] = q[(size_t)b * D_SZ + tid + 256];
  if(tid < F_SZ) fs[tid] = filt[b * F_SZ + tid];
  if(tid == F_SZ) fs[tid] = target[b];
  if(tid == 0) tbs = t[b];
  __syncthreads();
  const float tb = tbs;
  int c = 0;
  const int nend = (blockIdx.y + 1) * 2048 < N_SZ ? (blockIdx.y + 1) * 2048 : N_SZ;
  for(int n = blockIdx.y * 2048 + tid; n < nend; n += 256){
    float s = 0.f;
    for(int k = 0; k < D_SZ; k++) s += qs[k] * rhs[(size_t)k * N_SZ + n];
    if(s >= tb){
      bool m = false;
      for(int i = 0; i <= F_SZ; i++) if(fs[i] == n){ m = true; break; }
      if(!m) c++;
    }
  }
  for(int off = 32; off; off >>= 1) c += __shfl_down(c, off);
  __shared__ int red[4];
  if((tid & 63) == 0) red[tid >> 6] = c;
  __syncthreads();
  if(tid == 0){
    int s = red[0] + red[1] + red[2] + red[3];
    if(s) atomicAdd(&out[b], (float)s);
  }
}

extern "C" void kernel_launch(void* const* d_in, const int* in_sizes, int n_in,
                              void* d_out, int out_size, void* d_ws, size_t ws_size,
                              hipStream_t stream){
  const float* q    = (const float*)d_in[0];
  const float* rhs  = (const float*)d_in[1];
  const int* filt   = (const int*)d_in[2];
  const int* target = (const int*)d_in[3];
  float* out = (float*)d_out;
  char* ws = (char*)d_ws;
  float* t          = (float*)(ws + T_OFF);
  int* cnt          = (int*)(ws + CNT_OFF);
  unsigned* entries = (unsigned*)(ws + ENT_OFF);
  __bf16* qb        = (__bf16*)(ws + QB_OFF);
  __bf16* rhsT      = (__bf16*)(ws + RT_OFF);

  const size_t need = (size_t)RT_OFF + (size_t)RT_ROWS * D_SZ * 2;   // ~106.7 MB
  const bool big = ws_size >= need;

  zero_ws<<<32, 256, 0, stream>>>((int*)ws);
  t_kernel<<<B_SZ, 256, 0, stream>>>(q, rhs, target, t);
  prep_kernel<<<(B_SZ + 255) / 256, 256, 0, stream>>>(filt, target, t, cnt, entries, out);
  if(big){
    cvtq_kernel<<<256, 256, 0, stream>>>(q, qb);
    tconv_kernel<<<dim3(RT_ROWS / 64, 8), 256, 0, stream>>>(rhs, rhsT);
    main_kernel<<<G2, 512, 0, stream>>>(rhsT, qb, t, cnt, entries, out);
  } else {
    fallback_kernel<<<dim3(B_SZ, 49), 256, 0, stream>>>(q, rhs, filt, target, t, out);
  }
}

// Round 5
// 487.854 us; speedup vs baseline: 1.4397x; 1.2750x over previous
//
#include <hip/hip_runtime.h>
#include <hip/hip_bf16.h>
#include <cstdint>

#define B_SZ 1000
#define D_SZ 512
#define N_SZ 100000
#define F_SZ 50
#define NEGV -1000000.0f

// ---- 256x256 main tile geometry ----
#define BM2 256
#define NT_N2 391            // 391*256 = 100096
#define NT_B2 4              // 1024/256
#define G2 (NT_B2 * NT_N2)   // 1564 blocks
#define CAP2 160             // avg entries/bin ~32.6

#define T_OFF 0
#define CNT_OFF 4096
#define ENT_OFF 32768            // entries: 1564*160*4B = 1.0 MB (< 2MB gap)
#define QB_OFF  0x200000         // qb2: 4*8*8*256*16B = 1 MB (2 MB region)
#define RT_OFF  0x400000         // rhsT2: 391 * 256KB = 102.5 MB
#define RT_ROWS 100096

typedef __bf16 bf16x8 __attribute__((ext_vector_type(8)));
typedef float f32x4 __attribute__((ext_vector_type(4)));

__device__ __forceinline__ void gl_lds16(const void* g, void* l){
  __builtin_amdgcn_global_load_lds(
      (const __attribute__((address_space(1))) unsigned int*)g,
      (__attribute__((address_space(3))) unsigned int*)l, 16, 0, 0);
}

// ---------------- zero t/cnt regions (ws poisoned 0xAA each call) ----------
__global__ void zero_ws(int* p){ p[blockIdx.x * 256 + threadIdx.x] = 0; }

// ---------------- q f32 [1000][512] -> qb2 tiled bf16 ----------------------
// qb2 layout: [mt 4][kt 8][kq 8][row 256][8 bf16]  (LDS-tile order, pads 0)
__global__ void cvtq_kernel(const float* __restrict__ q, __bf16* __restrict__ qb){
  int g = blockIdx.x * 256 + threadIdx.x;
  int row = g >> 6;                 // 0..1023
  int k0 = (g & 63) * 8;
  float4 v0 = make_float4(0.f,0.f,0.f,0.f), v1 = v0;
  if(row < B_SZ){
    v0 = *(const float4*)(q + (size_t)row * D_SZ + k0);
    v1 = *(const float4*)(q + (size_t)row * D_SZ + k0 + 4);
  }
  bf16x8 w = { (__bf16)v0.x,(__bf16)v0.y,(__bf16)v0.z,(__bf16)v0.w,
               (__bf16)v1.x,(__bf16)v1.y,(__bf16)v1.z,(__bf16)v1.w };
  int mt = row >> 8, r = row & 255;
  int kt = k0 >> 6, kq = (k0 >> 3) & 7;
  *(bf16x8*)(qb + ((size_t)(mt*8 + kt)*8 + kq) * 2048 + (size_t)r * 8) = w;
}

// ---------------- rhs f32 [512][100000] -> rhsT2 tiled bf16 ----------------
// rhsT2 layout: [nt 391][kt 8][kq 8][row 256][8 bf16]
__global__ __launch_bounds__(256)
void tconv_kernel(const float* __restrict__ rhs, __bf16* __restrict__ rhsT){
  __shared__ float tile[64][65];
  const int tn = blockIdx.x;           // 0..1563
  const int tk = blockIdx.y;           // 0..7 (one k-tile per block)
  const int tid = threadIdx.x;
  const int n0 = tn * 64, k0 = tk * 64;
  // read phase: coalesced along n
  {
    const int nc = (tid & 15) * 4;
    const int kr0 = tid >> 4;          // 0..15
    #pragma unroll
    for(int i = 0; i < 4; i++){
      int kr = kr0 + i * 16;
      int n = n0 + nc;
      float4 v = (n < N_SZ) ? *(const float4*)(rhs + (size_t)(k0 + kr) * N_SZ + n)
                            : make_float4(0.f,0.f,0.f,0.f);
      tile[kr][nc+0] = v.x; tile[kr][nc+1] = v.y;
      tile[kr][nc+2] = v.z; tile[kr][nc+3] = v.w;
    }
  }
  __syncthreads();
  // write phase: lane = n (perfectly coalesced 1KB per kq region)
  {
    const int nl = tid & 63;
    const int kc = (tid >> 6) * 16;    // 0,16,32,48
    float a[16];
    #pragma unroll
    for(int j = 0; j < 16; j++) a[j] = tile[kc + j][nl];
    bf16x8 w0, w1;
    #pragma unroll
    for(int j = 0; j < 8; j++){ w0[j] = (__bf16)a[j]; w1[j] = (__bf16)a[8 + j]; }
    const int ng = n0 + nl;
    const int nt = ng >> 8, r = ng & 255;
    const int kq0 = kc >> 3;           // 0,2,4,6
    __bf16* dst = rhsT + ((size_t)(nt*8 + tk)*8 + kq0) * 2048 + (size_t)r * 8;
    *(bf16x8*)dst = w0;
    *(bf16x8*)(dst + 2048) = w1;       // kq0+1
  }
}

// ---------------- t[b] = q[b] . rhs[:, target[b]] (f32 exact) --------------
__global__ void t_kernel(const float* __restrict__ q, const float* __restrict__ rhs,
                         const int* __restrict__ target, float* __restrict__ t){
  int b = blockIdx.x;
  int tid = threadIdx.x;
  int tj = target[b];
  const float* qb = q + (size_t)b * D_SZ;
  float p = qb[tid] * rhs[(size_t)tid * N_SZ + tj]
          + qb[tid + 256] * rhs[(size_t)(tid + 256) * N_SZ + tj];
  for(int off = 32; off; off >>= 1) p += __shfl_down(p, off);
  __shared__ float red[4];
  if((tid & 63) == 0) red[tid >> 6] = p;
  __syncthreads();
  if(tid == 0) t[b] = red[0] + red[1] + red[2] + red[3];
}

// ---------------- dedupe filter∪target, bin into owning 256x256 tile -------
// Wave-parallel: shuffle-based first-occurrence test, no scratch arrays.
__global__ __launch_bounds__(64)
void prep_kernel(const int* __restrict__ filt, const int* __restrict__ target,
                 const float* __restrict__ t, int* __restrict__ cnt,
                 unsigned* __restrict__ entries, float* __restrict__ out){
  const int b = blockIdx.x;
  const int lane = threadIdx.x;      // 64 lanes, one wave
  int v = 0x7fffffff;
  if(lane < F_SZ) v = filt[b * F_SZ + lane];
  else if(lane == F_SZ) v = target[b];
  const bool active = lane <= F_SZ;
  bool first = active;
  #pragma unroll 1
  for(int k = 0; k < F_SZ; k++){     // lane>k duplicates of lane k are not-first
    int o = __shfl(v, k);
    if(active && k < lane && o == v) first = false;
  }
  if(first){
    int bid = (b >> 8) * NT_N2 + (v >> 8);
    int pos = atomicAdd(&cnt[bid], 1);
    if(pos < CAP2)
      entries[(size_t)bid * CAP2 + pos] = (unsigned)(((b & 255) << 8) | (v & 255));
  }
  int nuniq = (int)__popcll(__ballot(first));
  if(lane == 0){
    float tb = t[b];
    out[b] = 1.0f + ((NEGV >= tb) ? (float)nuniq : 0.0f);
  }
}

// ---------------- fused 256x256 MFMA GEMM + rank count (8-phase m201) ------
// 8 waves (2M x 4N), per-wave 128x64 C (acc[8][4] f32x4). BK=64, 8 K-tiles.
// Per K-tile: 4 phases, one C-quadrant each (16 MFMA), operand regs reused
// across phases (A read once per row-half, B once per col-half = 24 b128/wave
// per K-tile, the data minimum). Each phase: {mem window: ds_reads + gl_lds
// staging} -> s_barrier -> setprio(1) MFMA x16 setprio(0) -> s_barrier.
// Staging of tile kt+1 front-loaded into phases 0-1; the per-K-tile
// vmcnt(0) in phase 3 therefore guards loads issued 2-3 phases earlier.
// End-of-tile barrier carries an explicit lgkmcnt(0) (write-after-read fence
// for the buffer the next tile's staging overwrites).
__global__ __launch_bounds__(512, 2)
void main_kernel(const __bf16* __restrict__ rhsT, const __bf16* __restrict__ qb,
                 const float* __restrict__ t, const int* __restrict__ cnt,
                 const unsigned* __restrict__ entries, float* __restrict__ out){
  __shared__ __attribute__((aligned(16))) __bf16 A2[2][16384];  // 64 KB
  __shared__ __attribute__((aligned(16))) __bf16 B2[2][16384];  // 64 KB
  __shared__ float tl[256];
  __shared__ unsigned lent[CAP2];
  __shared__ unsigned bm[2048];      // 256 rows x 256 cols bit map (8 KB)
  __shared__ int rowc[256];
  __shared__ int lcnt_s;

  // ---- bijective XCD swizzle (nwg=1564 = 8*195+4): 4 consecutive wg
  // (the 4 tile_b sharers of one B-strip) land on one XCD.
  const int h = blockIdx.x;
  const int xcd = h & 7, slot = h >> 3;
  const int wg = (xcd < 4 ? xcd * 196 : 784 + (xcd - 4) * 195) + slot;
  const int tile_n = wg >> 2;        // 0..390
  const int tile_b = wg & 3;         // 0..3
  const int bid = tile_b * NT_N2 + tile_n;
  const int tid = threadIdx.x;
  const int n0 = tile_n * BM2;
  const int b0 = tile_b * BM2;

  if(tid < 256){ int b = b0 + tid; tl[tid] = (b < B_SZ) ? t[b] : 0.f; rowc[tid] = 0; }
  if(tid < CAP2) lent[tid] = entries[(size_t)bid * CAP2 + tid];
  if(tid == 0){ int c = cnt[bid]; lcnt_s = (c > CAP2) ? CAP2 : c; }
  bm[tid] = 0; bm[tid + 512] = 0; bm[tid + 1024] = 0; bm[tid + 1536] = 0;

  const int wave = tid >> 6, lane = tid & 63;
  const int quad = lane >> 4, l15 = lane & 15;
  const int wm = wave >> 2, wn = wave & 3;   // 2 x 4 wave grid

  // staging source pointers (linear copy: global layout == LDS layout)
  const __bf16* pA = qb   + (size_t)tile_b * 131072 + (size_t)tid * 8;
  const __bf16* pB = rhsT + (size_t)tile_n * 131072 + (size_t)tid * 8;

  f32x4 acc[8][4];
  #pragma unroll
  for(int i = 0; i < 8; i++)
    #pragma unroll
    for(int j = 0; j < 4; j++)
      acc[i][j] = (f32x4){0.f, 0.f, 0.f, 0.f};

  __syncthreads();                 // tables resident; drains table-load vmcnt
  {                                // mark filter bitmap (LDS atomics)
    int lc = lcnt_s;
    if(tid < lc){
      unsigned en = lent[tid];
      unsigned row = en >> 8, col = en & 255;
      atomicOr(&bm[row * 8 + (col >> 5)], 1u << (col & 31));
    }
  }
  // ---- prologue: stage K-tile 0 into buffer 0 (one-time full drain)
  #pragma unroll
  for(int o = 0; o < 4; o++){
    gl_lds16(pA + o * 4096, &A2[0][o * 4096 + tid * 8]);
    gl_lds16(pB + o * 4096, &B2[0][o * 4096 + tid * 8]);
  }
  pA += 16384; pB += 16384;
  asm volatile("s_waitcnt vmcnt(0)" ::: "memory");
  __builtin_amdgcn_s_barrier();
  asm volatile("" ::: "memory");

  bf16x8 a8[2][4];                 // A frags: [ks][row-subtile] (one row-half)
  bf16x8 b4[2][2];                 // B frags: [ks][col-subtile] (one col-half)

  #pragma unroll 1
  for(int kt = 0; kt < 8; kt++){
    const int cur = kt & 1, nxt = cur ^ 1;
    const __bf16* baA = &A2[cur][quad * 2048 + (size_t)(wm * 128 + l15) * 8];
    const __bf16* baB = &B2[cur][quad * 2048 + (size_t)(wn * 64  + l15) * 8];

    // ===== phase 0: quadrant (rows 0-63, cols 0-31) =====
    #pragma unroll
    for(int ks = 0; ks < 2; ks++){
      #pragma unroll
      for(int i = 0; i < 4; i++) a8[ks][i] = *(const bf16x8*)(baA + ks * 8192 + i * 128);
      #pragma unroll
      for(int j = 0; j < 2; j++) b4[ks][j] = *(const bf16x8*)(baB + ks * 8192 + j * 128);
    }
    if(kt < 7){                    // stage A(kt+1), 4 loads
      #pragma unroll
      for(int o = 0; o < 4; o++) gl_lds16(pA + o * 4096, &A2[nxt][o * 4096 + tid * 8]);
    }
    __builtin_amdgcn_s_barrier();
    asm volatile("" ::: "memory");
    __builtin_amdgcn_s_setprio(1);
    #pragma unroll
    for(int ks = 0; ks < 2; ks++)
      #pragma unroll
      for(int i = 0; i < 4; i++)
        #pragma unroll
        for(int j = 0; j < 2; j++)
          acc[i][j] = __builtin_amdgcn_mfma_f32_16x16x32_bf16(a8[ks][i], b4[ks][j], acc[i][j], 0, 0, 0);
    __builtin_amdgcn_s_setprio(0);
    __builtin_amdgcn_s_barrier();
    asm volatile("" ::: "memory");

    // ===== phase 1: quadrant (rows 0-63, cols 32-63), reuse A =====
    #pragma unroll
    for(int ks = 0; ks < 2; ks++)
      #pragma unroll
      for(int j = 0; j < 2; j++) b4[ks][j] = *(const bf16x8*)(baB + ks * 8192 + 256 + j * 128);
    if(kt < 7){                    // stage B(kt+1), 4 loads
      #pragma unroll
      for(int o = 0; o < 4; o++) gl_lds16(pB + o * 4096, &B2[nxt][o * 4096 + tid * 8]);
      pA += 16384; pB += 16384;
    }
    __builtin_amdgcn_s_barrier();
    asm volatile("" ::: "memory");
    __builtin_amdgcn_s_setprio(1);
    #pragma unroll
    for(int ks = 0; ks < 2; ks++)
      #pragma unroll
      for(int i = 0; i < 4; i++)
        #pragma unroll
        for(int j = 0; j < 2; j++)
          acc[i][2+j] = __builtin_amdgcn_mfma_f32_16x16x32_bf16(a8[ks][i], b4[ks][j], acc[i][2+j], 0, 0, 0);
    __builtin_amdgcn_s_setprio(0);
    __builtin_amdgcn_s_barrier();
    asm volatile("" ::: "memory");

    // ===== phase 2: quadrant (rows 64-127, cols 32-63), reuse B =====
    #pragma unroll
    for(int ks = 0; ks < 2; ks++)
      #pragma unroll
      for(int i = 0; i < 4; i++) a8[ks][i] = *(const bf16x8*)(baA + ks * 8192 + 512 + i * 128);
    __builtin_amdgcn_s_barrier();
    asm volatile("" ::: "memory");
    __builtin_amdgcn_s_setprio(1);
    #pragma unroll
    for(int ks = 0; ks < 2; ks++)
      #pragma unroll
      for(int i = 0; i < 4; i++)
        #pragma unroll
        for(int j = 0; j < 2; j++)
          acc[4+i][2+j] = __builtin_amdgcn_mfma_f32_16x16x32_bf16(a8[ks][i], b4[ks][j], acc[4+i][2+j], 0, 0, 0);
    __builtin_amdgcn_s_setprio(0);
    __builtin_amdgcn_s_barrier();
    asm volatile("" ::: "memory");

    // ===== phase 3: quadrant (rows 64-127, cols 0-31), reuse A =====
    #pragma unroll
    for(int ks = 0; ks < 2; ks++)
      #pragma unroll
      for(int j = 0; j < 2; j++) b4[ks][j] = *(const bf16x8*)(baB + ks * 8192 + j * 128);
    if(kt < 7)                     // tile kt+1 loads (issued phases 0-1) resident
      asm volatile("s_waitcnt vmcnt(0)" ::: "memory");
    __builtin_amdgcn_s_barrier();
    asm volatile("" ::: "memory");
    __builtin_amdgcn_s_setprio(1);
    #pragma unroll
    for(int ks = 0; ks < 2; ks++)
      #pragma unroll
      for(int i = 0; i < 4; i++)
        #pragma unroll
        for(int j = 0; j < 2; j++)
          acc[4+i][j] = __builtin_amdgcn_mfma_f32_16x16x32_bf16(a8[ks][i], b4[ks][j], acc[4+i][j], 0, 0, 0);
    __builtin_amdgcn_s_setprio(0);
    // end-of-tile fence: all my LDS reads of buf[cur] complete before the
    // barrier, so tile kt+1's staging may overwrite buf[cur] after it.
    asm volatile("s_waitcnt lgkmcnt(0)" ::: "memory");
    __builtin_amdgcn_s_barrier();
    asm volatile("" ::: "memory");
  }

  // ---- epilogue: count s >= t_row, excluding bitmap-marked filter entries --
  // C/D layout: col = l15 (+16j), row = quad*4 + r (+16i) [verified mapping]
  #pragma unroll
  for(int i = 0; i < 8; i++){
    #pragma unroll
    for(int r = 0; r < 4; r++){
      const int row = wm*128 + i*16 + quad*4 + r;
      const float trow = tl[row];
      const unsigned w01 = bm[row * 8 + wn * 2];
      const unsigned w23 = bm[row * 8 + wn * 2 + 1];
      int c = 0;
      bool ge[4];
      #pragma unroll
      for(int j = 0; j < 4; j++){
        int ncol = n0 + wn*64 + j*16 + l15;
        ge[j] = (ncol < N_SZ) && (acc[i][j][r] >= trow);
        c += ge[j] ? 1 : 0;
      }
      if(w01 | w23){                      // rare
        #pragma unroll
        for(int j = 0; j < 4; j++){
          unsigned w = (j < 2) ? w01 : w23;
          if(((w >> ((j & 1) * 16 + l15)) & 1u) && ge[j]) c--;
        }
      }
      c += __shfl_xor(c, 1);
      c += __shfl_xor(c, 2);
      c += __shfl_xor(c, 4);
      c += __shfl_xor(c, 8);
      if(l15 == 0) atomicAdd(&rowc[row], c);
    }
  }
  __syncthreads();
  if(tid < 256){
    int bg = b0 + tid, c = rowc[tid];
    if(bg < B_SZ && c) atomicAdd(&out[bg], (float)c);
  }
}

// ---------------- correctness fallback (small ws): plain f32 counting ------
__global__ __launch_bounds__(256)
void fallback_kernel(const float* __restrict__ q, const float* __restrict__ rhs,
                     const int* __restrict__ filt, const int* __restrict__ target,
                     const float* __restrict__ t, float* __restrict__ out){
  const int b = blockIdx.x;
  const int tid = threadIdx.x;
  __shared__ float qs[D_SZ];
  __shared__ int fs[F_SZ + 1];
  __shared__ float tbs;
  qs[tid] = q[(size_t)b * D_SZ + tid];
  qs[tid + 256] = q[(size_t)b * D_SZ + tid + 256];
  if(tid < F_SZ) fs[tid] = filt[b * F_SZ + tid];
  if(tid == F_SZ) fs[tid] = target[b];
  if(tid == 0) tbs = t[b];
  __syncthreads();
  const float tb = tbs;
  int c = 0;
  const int nend = (blockIdx.y + 1) * 2048 < N_SZ ? (blockIdx.y + 1) * 2048 : N_SZ;
  for(int n = blockIdx.y * 2048 + tid; n < nend; n += 256){
    float s = 0.f;
    for(int k = 0; k < D_SZ; k++) s += qs[k] * rhs[(size_t)k * N_SZ + n];
    if(s >= tb){
      bool m = false;
      for(int i = 0; i <= F_SZ; i++) if(fs[i] == n){ m = true; break; }
      if(!m) c++;
    }
  }
  for(int off = 32; off; off >>= 1) c += __shfl_down(c, off);
  __shared__ int red[4];
  if((tid & 63) == 0) red[tid >> 6] = c;
  __syncthreads();
  if(tid == 0){
    int s = red[0] + red[1] + red[2] + red[3];
    if(s) atomicAdd(&out[b], (float)s);
  }
}

extern "C" void kernel_launch(void* const* d_in, const int* in_sizes, int n_in,
                              void* d_out, int out_size, void* d_ws, size_t ws_size,
                              hipStream_t stream){
  const float* q    = (const float*)d_in[0];
  const float* rhs  = (const float*)d_in[1];
  const int* filt   = (const int*)d_in[2];
  const int* target = (const int*)d_in[3];
  float* out = (float*)d_out;
  char* ws = (char*)d_ws;
  float* t          = (float*)(ws + T_OFF);
  int* cnt          = (int*)(ws + CNT_OFF);
  unsigned* entries = (unsigned*)(ws + ENT_OFF);
  __bf16* qb        = (__bf16*)(ws + QB_OFF);
  __bf16* rhsT      = (__bf16*)(ws + RT_OFF);

  const size_t need = (size_t)RT_OFF + (size_t)RT_ROWS * D_SZ * 2;   // ~106.7 MB
  const bool big = ws_size >= need;

  zero_ws<<<32, 256, 0, stream>>>((int*)ws);
  t_kernel<<<B_SZ, 256, 0, stream>>>(q, rhs, target, t);
  prep_kernel<<<B_SZ, 64, 0, stream>>>(filt, target, t, cnt, entries, out);
  if(big){
    cvtq_kernel<<<256, 256, 0, stream>>>(q, qb);
    tconv_kernel<<<dim3(RT_ROWS / 64, 8), 256, 0, stream>>>(rhs, rhsT);
    main_kernel<<<G2, 512, 0, stream>>>(rhsT, qb, t, cnt, entries, out);
  } else {
    fallback_kernel<<<dim3(B_SZ, 49), 256, 0, stream>>>(q, rhs, filt, target, t, out);
  }
}